// Round 10
// baseline (350.338 us; speedup 1.0000x reference)
//
#include <hip/hip_runtime.h>
#include <hip/hip_bf16.h>
#include <math.h>

#define Bq 32
#define Tt 1024
#define Hh 512
#define Vv 1024
#define Ss 128

typedef short bf16x8 __attribute__((ext_vector_type(8)));
typedef float f32x4 __attribute__((ext_vector_type(4)));

#define GLDS(srcp, dstp, sz) \
  __builtin_amdgcn_global_load_lds( \
      (const __attribute__((address_space(1))) void*)(srcp), \
      (__attribute__((address_space(3))) void*)(dstp), sz, 0, 0)

__device__ __forceinline__ ushort f2bf(float v) {
  __hip_bfloat16 hv = __float2bfloat16(v);
  return *(ushort*)&hv;
}

// wait until <=N of this wave's VMEM ops outstanding, then raw workgroup barrier
template <int N>
__device__ __forceinline__ void wb() {
  __asm__ volatile("s_waitcnt vmcnt(%0)" ::"i"(N) : "memory");
  __builtin_amdgcn_s_barrier();
}

// butterfly sum over the 16-lane r16 group
#define BFLY_ADD(v) { \
  v += __int_as_float(__builtin_amdgcn_ds_swizzle(__float_as_int(v), 0x041F)); \
  v += __int_as_float(__builtin_amdgcn_ds_swizzle(__float_as_int(v), 0x081F)); \
  v += __int_as_float(__builtin_amdgcn_ds_swizzle(__float_as_int(v), 0x101F)); \
  v += __int_as_float(__builtin_amdgcn_ds_swizzle(__float_as_int(v), 0x201F)); }

// ---- merged transpose + fp32->bf16 for W1 and W2 in ONE dispatch ----
__global__ void transpose_cvt2(const float* __restrict__ W1, const float* __restrict__ W2,
                               ushort* __restrict__ W1T, ushort* __restrict__ W2T) {
  __shared__ float tile[32][33];
  const int bid = blockIdx.x;
  const float* in; ushort* out; int K, N, bx, by;
  if (bid < 256) { in = W1; out = W1T; K = Hh; N = Hh; bx = bid & 15; by = bid >> 4; }
  else { const int b2 = bid - 256; in = W2; out = W2T; K = Hh; N = Vv; bx = b2 & 31; by = b2 >> 5; }
  const int k0 = by * 32, n0 = bx * 32;
  const int tx = threadIdx.x, ty = threadIdx.y;
  for (int i = ty; i < 32; i += 8)
    tile[i][tx] = in[(size_t)(k0 + i) * N + n0 + tx];
  __syncthreads();
  for (int i = ty; i < 32; i += 8)
    out[(size_t)(n0 + i) * K + k0 + tx] = f2bf(tile[tx][i]);
}

// ---- GEMM1: h = tanh(X @ W1T^T + b1) ----
// 64 rows/block; A-frags once from fp32 X into regs; B 3-buffered via GLDS
// (48 KB LDS -> 3 blocks/CU), raw-barrier vmcnt(4) pipeline + register B-frag
// prefetch; bias software-prefetched per tile.
__global__ __launch_bounds__(256, 3)
void gemm1_fused(const float* __restrict__ X, const ushort* __restrict__ Bt,
                 const float* __restrict__ bias, const int* __restrict__ lens,
                 ushort* __restrict__ H) {
  __shared__ ushort Bs[3][128 * 64];          // 48 KB
  const int row0 = blockIdx.x * 64;
  if ((row0 & (Tt - 1)) >= lens[blockIdx.x >> 4]) return;

  const int tid = threadIdx.x;
  const int lane = tid & 63, wave = tid >> 6;
  const int wm = wave >> 1, wn = wave & 1;
  const int q = lane >> 4, r16 = lane & 15;
  const int lrow = lane >> 3;
  const int swz = (lane & 7) ^ lrow;
  const int rx = r16 & 7;
  const int kx0 = (q ^ rx) * 8;
  const int kx1 = ((4 + q) ^ rx) * 8;

  bf16x8 af[16][2];
#pragma unroll
  for (int ks = 0; ks < 16; ++ks)
#pragma unroll
    for (int mi = 0; mi < 2; ++mi) {
      const float* src = X + (size_t)(row0 + wm * 32 + mi * 16 + r16) * Hh + ks * 32 + q * 8;
      const float4 f0 = *(const float4*)(src);
      const float4 f1 = *(const float4*)(src + 4);
      union { bf16x8 v; ushort u[8]; } pk;
      pk.u[0] = f2bf(f0.x); pk.u[1] = f2bf(f0.y); pk.u[2] = f2bf(f0.z); pk.u[3] = f2bf(f0.w);
      pk.u[4] = f2bf(f1.x); pk.u[5] = f2bf(f1.y); pk.u[6] = f2bf(f1.z); pk.u[7] = f2bf(f1.w);
      af[ks][mi] = pk.v;
    }

  auto stageF = [&](int nt2, int kc2, int d2) {
#pragma unroll
    for (int i = 0; i < 4; ++i) {
      const int seg = wave * 4 + i;
      const int rr = seg * 8 + lrow;
      GLDS(Bt + (size_t)(nt2 * 128 + rr) * Hh + kc2 * 64 + swz * 8, &Bs[d2][seg * 512], 16);
    }
  };
  auto readFrags = [&](bf16x8 (&bfr)[2][4], int d) {
#pragma unroll
    for (int ni = 0; ni < 4; ++ni) {
      bfr[0][ni] = *(const bf16x8*)(&Bs[d][((wn * 64 + ni * 16 + r16) << 6) + kx0]);
      bfr[1][ni] = *(const bf16x8*)(&Bs[d][((wn * 64 + ni * 16 + r16) << 6) + kx1]);
    }
  };

  stageF(0, 0, 0);
  stageF(0, 1, 1);
  wb<4>();
  bf16x8 bcur[2][4], bnxt[2][4];
  readFrags(bcur, 0);

  f32x4 acc[2][4];
#pragma unroll
  for (int i = 0; i < 2; ++i)
#pragma unroll
    for (int j = 0; j < 4; ++j) acc[i][j] = (f32x4){0.f, 0.f, 0.f, 0.f};

  float bcol[4];
  for (int nt = 0; nt < 4; ++nt) {
    const int b0 = (nt * 8) % 3;
#pragma unroll
    for (int kc = 0; kc < 8; ++kc) {
      int cb = b0 + (kc % 3); if (cb >= 3) cb -= 3;        // consume buffer
      int nb = b0 + ((kc + 1) % 3); if (nb >= 3) nb -= 3;  // next buffer
      int sb = b0 + ((kc + 2) % 3); if (sb >= 3) sb -= 3;  // stage target
      if (kc == 0) {   // software-prefetch bias for this tile
#pragma unroll
        for (int ni = 0; ni < 4; ++ni) bcol[ni] = bias[nt * 128 + wn * 64 + ni * 16 + r16];
      }
      const bool haveS = !(nt == 3 && kc >= 6);
      const bool haveN = !(nt == 3 && kc == 7);
      if (haveS) stageF(nt + (kc >= 6 ? 1 : 0), (kc + 2) & 7, sb);
      if (haveN) {
        if (haveS) wb<4>(); else wb<0>();
        readFrags(bnxt, nb);
      }
#pragma unroll
      for (int ksl = 0; ksl < 2; ++ksl)
#pragma unroll
        for (int mi = 0; mi < 2; ++mi)
#pragma unroll
          for (int ni = 0; ni < 4; ++ni)
            acc[mi][ni] = __builtin_amdgcn_mfma_f32_16x16x32_bf16(af[kc * 2 + ksl][mi], bcur[ksl][ni], acc[mi][ni], 0, 0, 0);
#pragma unroll
      for (int z = 0; z < 2; ++z)
#pragma unroll
        for (int ni = 0; ni < 4; ++ni) bcur[z][ni] = bnxt[z][ni];
      if (kc == 7) {
#pragma unroll
        for (int mi = 0; mi < 2; ++mi)
#pragma unroll
          for (int r = 0; r < 4; ++r) {
            const int row = row0 + wm * 32 + mi * 16 + q * 4 + r;
#pragma unroll
            for (int ni = 0; ni < 4; ++ni) {
              const float v = acc[mi][ni][r] + bcol[ni];
              const float ex = __expf(2.0f * v);       // tanh=(e^2x-1)/(e^2x+1)
              const float th = (ex - 1.0f) / (ex + 1.0f);
              H[(size_t)row * Hh + nt * 128 + wn * 64 + ni * 16 + r16] = f2bf(th);
            }
            acc[mi][0][r] = 0.f; acc[mi][1][r] = 0.f; acc[mi][2][r] = 0.f; acc[mi][3][r] = 0.f;
          }
      }
    }
  }
}

// ---- GEMM2 + bias + softmax (no-max: |logit|<~2) + label gather, fused ----
// Same 3-buffer pipeline; bias via register software-prefetch (no biasLds).
__global__ __launch_bounds__(256, 3)
void gemm2sm(const ushort* __restrict__ Aq, const ushort* __restrict__ Bt,
             const float* __restrict__ bias, const int* __restrict__ tgt,
             const int* __restrict__ lens,
             ushort* __restrict__ pOdd, ushort* __restrict__ pBlank) {
  __shared__ ushort Bs[3][128 * 64];          // 48 KB
  __shared__ int tgLds[128];
  __shared__ float blankL[64];
  __shared__ float rowSum[64];
  __shared__ float tmpP[2][64];

  const int row0 = blockIdx.x * 64;
  const int bEx = blockIdx.x >> 4;
  if ((row0 & (Tt - 1)) >= lens[bEx]) return;

  const int tid = threadIdx.x;
  const int lane = tid & 63, wave = tid >> 6;
  const int wm = wave >> 1, wn = wave & 1;
  const int q = lane >> 4, r16 = lane & 15;
  const int lrow = lane >> 3;
  const int swz = (lane & 7) ^ lrow;
  const int rx = r16 & 7;
  const int kx0 = (q ^ rx) * 8;
  const int kx1 = ((4 + q) ^ rx) * 8;

  bf16x8 af[16][2];
#pragma unroll
  for (int ks = 0; ks < 16; ++ks)
#pragma unroll
    for (int mi = 0; mi < 2; ++mi)
      af[ks][mi] = *(const bf16x8*)(Aq + (size_t)(row0 + wm * 32 + mi * 16 + r16) * Hh + ks * 32 + q * 8);

  if (tid < 128) tgLds[tid] = tgt[bEx * Ss + tid];

  auto stageF = [&](int nt2, int kc2, int d2) {
#pragma unroll
    for (int i = 0; i < 4; ++i) {
      const int seg = wave * 4 + i;
      const int rr = seg * 8 + lrow;
      const ushort* src = (nt2 < 8)
          ? Bt + (size_t)(nt2 * 128 + rr) * Hh + kc2 * 64 + swz * 8
          : Bt + (size_t)tgLds[rr] * Hh + kc2 * 64 + swz * 8;
      GLDS(src, &Bs[d2][seg * 512], 16);
    }
  };
  auto readFrags = [&](bf16x8 (&bfr)[2][4], int d) {
#pragma unroll
    for (int ni = 0; ni < 4; ++ni) {
      bfr[0][ni] = *(const bf16x8*)(&Bs[d][((wn * 64 + ni * 16 + r16) << 6) + kx0]);
      bfr[1][ni] = *(const bf16x8*)(&Bs[d][((wn * 64 + ni * 16 + r16) << 6) + kx1]);
    }
  };

  stageF(0, 0, 0);
  stageF(0, 1, 1);
  __asm__ volatile("s_waitcnt lgkmcnt(0)" ::: "memory");  // tgLds writes done
  wb<4>();
  bf16x8 bcur[2][4], bnxt[2][4];
  readFrags(bcur, 0);

  f32x4 acc[2][4];
#pragma unroll
  for (int i = 0; i < 2; ++i)
#pragma unroll
    for (int j = 0; j < 4; ++j) acc[i][j] = (f32x4){0.f, 0.f, 0.f, 0.f};
  float rowP[2][4] = {{0.f, 0.f, 0.f, 0.f}, {0.f, 0.f, 0.f, 0.f}};

  float bcol[4];
  for (int nt = 0; nt < 9; ++nt) {
    const int b0 = (nt * 8) % 3;
#pragma unroll
    for (int kc = 0; kc < 8; ++kc) {
      int cb = b0 + (kc % 3); if (cb >= 3) cb -= 3;
      int nb = b0 + ((kc + 1) % 3); if (nb >= 3) nb -= 3;
      int sb = b0 + ((kc + 2) % 3); if (sb >= 3) sb -= 3;
      if (kc == 0) {   // software-prefetch bias for this tile's epilogue
#pragma unroll
        for (int ni = 0; ni < 4; ++ni)
          bcol[ni] = (nt < 8) ? bias[nt * 128 + wn * 64 + ni * 16 + r16]
                              : bias[tgLds[wn * 64 + ni * 16 + r16]];
      }
      const bool haveS = !(nt == 8 && kc >= 6);
      const bool haveN = !(nt == 8 && kc == 7);
      if (haveS) stageF(nt + (kc >= 6 ? 1 : 0), (kc + 2) & 7, sb);
      if (haveN) {
        if (haveS) wb<4>(); else wb<0>();
        readFrags(bnxt, nb);
      }
#pragma unroll
      for (int ksl = 0; ksl < 2; ++ksl)
#pragma unroll
        for (int mi = 0; mi < 2; ++mi)
#pragma unroll
          for (int ni = 0; ni < 4; ++ni)
            acc[mi][ni] = __builtin_amdgcn_mfma_f32_16x16x32_bf16(af[kc * 2 + ksl][mi], bcur[ksl][ni], acc[mi][ni], 0, 0, 0);
#pragma unroll
      for (int z = 0; z < 2; ++z)
#pragma unroll
        for (int ni = 0; ni < 4; ++ni) bcur[z][ni] = bnxt[z][ni];

      if (kc == 7) {
        if (nt < 8) {
          if (nt == 0 && wn == 0 && r16 == 0) {
#pragma unroll
            for (int mi = 0; mi < 2; ++mi)
#pragma unroll
              for (int r = 0; r < 4; ++r)
                blankL[wm * 32 + mi * 16 + q * 4 + r] = acc[mi][0][r] + bcol[0];
          }
#pragma unroll
          for (int mi = 0; mi < 2; ++mi)
#pragma unroll
            for (int r = 0; r < 4; ++r) {
              float s = __expf(acc[mi][0][r] + bcol[0]);
              s += __expf(acc[mi][1][r] + bcol[1]);
              s += __expf(acc[mi][2][r] + bcol[2]);
              s += __expf(acc[mi][3][r] + bcol[3]);
              rowP[mi][r] += s;
              acc[mi][0][r] = 0.f; acc[mi][1][r] = 0.f; acc[mi][2][r] = 0.f; acc[mi][3][r] = 0.f;
            }
          if (nt == 7) {
            float sred[2][4];
#pragma unroll
            for (int mi = 0; mi < 2; ++mi)
#pragma unroll
              for (int r = 0; r < 4; ++r) {
                float s = rowP[mi][r];
                BFLY_ADD(s);
                sred[mi][r] = s;
              }
            if (r16 == 0) {
#pragma unroll
              for (int mi = 0; mi < 2; ++mi) {
                float4 w = {sred[mi][0], sred[mi][1], sred[mi][2], sred[mi][3]};
                *(float4*)&tmpP[wn][wm * 32 + mi * 16 + q * 4] = w;
              }
            }
            __syncthreads();
            if (tid < 64) {
              const float tot = tmpP[0][tid] + tmpP[1][tid];
              rowSum[tid] = tot;
              pBlank[row0 + tid] = f2bf(__expf(blankL[tid]) * 64.0f / tot);
            }
            __syncthreads();
          }
        } else {
          // label tile: p = exp(logit)/rowSum, prescaled by 2^6
#pragma unroll
          for (int mi = 0; mi < 2; ++mi) {
            const float4 rs4 = *(const float4*)&rowSum[wm * 32 + mi * 16 + q * 4];
#pragma unroll
            for (int r = 0; r < 4; ++r) {
              const float sc = 64.0f / ((const float*)&rs4)[r];
              const int row = row0 + wm * 32 + mi * 16 + q * 4 + r;
#pragma unroll
              for (int ni = 0; ni < 4; ++ni) {
                const float p = __expf(acc[mi][ni][r] + bcol[ni]) * sc;
                pOdd[(size_t)row * Ss + wn * 64 + ni * 16 + r16] = f2bf(p);
              }
            }
          }
        }
      }
    }
  }
}

// ---- DPP helpers ----
__device__ __forceinline__ float dpp_wshr1(float x) {
  return __int_as_float(__builtin_amdgcn_update_dpp(
      0, __float_as_int(x), 0x138, 0xf, 0xf, true));
}
__device__ __forceinline__ float dpp_wave_max(float m) {
  m = fmaxf(m, __int_as_float(__builtin_amdgcn_update_dpp(0, __float_as_int(m), 0x111, 0xf, 0xf, true)));
  m = fmaxf(m, __int_as_float(__builtin_amdgcn_update_dpp(0, __float_as_int(m), 0x112, 0xf, 0xf, true)));
  m = fmaxf(m, __int_as_float(__builtin_amdgcn_update_dpp(0, __float_as_int(m), 0x114, 0xf, 0xf, true)));
  m = fmaxf(m, __int_as_float(__builtin_amdgcn_update_dpp(0, __float_as_int(m), 0x118, 0xf, 0xf, true)));
  m = fmaxf(m, __int_as_float(__builtin_amdgcn_update_dpp(__float_as_int(m), __float_as_int(m), 0x142, 0xf, 0xf, false)));
  m = fmaxf(m, __int_as_float(__builtin_amdgcn_update_dpp(__float_as_int(m), __float_as_int(m), 0x143, 0xf, 0xf, false)));
  return __int_as_float(__builtin_amdgcn_readlane(__float_as_int(m), 63));
}

// ---- CTC forward DP: 4 states/lane (+256 on lane63), DPP halo,
// padded double-buffered LDS staging, 8-deep pipeline, unrolled 64-step chunks.
__global__ __launch_bounds__(64)
void ctc_dp(const ushort* __restrict__ pOddG, const ushort* __restrict__ pBlankG,
            const int* __restrict__ tgt, const int* __restrict__ lens,
            float* __restrict__ out) {
  __shared__ ushort pO[2][72 * 128];
  __shared__ ushort pBl[2][128];
  const int b = blockIdx.x, l = threadIdx.x;
  const ushort* pObase = pOddG + (size_t)b * Tt * Ss;
  const ushort* pBbase = pBlankG + (size_t)b * Tt;
  const int* tg = tgt + b * Ss;
  const int len = lens[b];

  float sk1 = 0.f, sk3;
  if (l >= 1) sk1 = (tg[2 * l] != tg[2 * l - 1]) ? 1.f : 0.f;
  sk3 = (tg[2 * l + 1] != tg[2 * l]) ? 1.f : 0.f;

  auto stage = [&](int c, int d) {
    const ushort* src = pObase + (size_t)c * 64 * 128;
#pragma unroll
    for (int i = 0; i < 16; ++i)
      GLDS(src + (i * 64 + l) * 8, &pO[d][i * 512], 16);
    GLDS(pBbase + c * 64 + l * 2, &pBl[d][0], 4);
  };

  stage(0, 0);
  __syncthreads();

  float a0 = 0.f, a1 = 0.f, a2 = 0.f, a3 = 0.f, a4 = 0.f;
  if (l == 0) {
    a0 = __int_as_float(((unsigned)pBl[0][0]) << 16);
    a1 = __int_as_float(((unsigned)pO[0][0]) << 16);
  }
  int E = 0;

  auto renorm = [&]() {
    float m = fmaxf(fmaxf(fmaxf(a0, a1), fmaxf(a2, a3)), a4);
    const float gm = dpp_wave_max(m);
    const int e = (int)((__float_as_uint(gm) >> 23) & 255) - 127;
    int sh = 30 - e; if (sh > 120) sh = 120;
    const float scale = __uint_as_float((unsigned)(127 + sh) << 23);
    E -= sh;
    a0 *= scale; a1 *= scale; a2 *= scale; a3 *= scale; a4 *= scale;
  };

  auto run_dyn = [&](int d, int stA, int stB, int tbase) {
    const int n = stB - stA;
    if (n <= 0) return;
    unsigned qL[4], qB[4];
#pragma unroll
    for (int k = 0; k < 4; ++k) {
      const int st = stA + k;
      qL[k] = *(const unsigned*)&pO[d][(st << 7) + 2 * l];
      qB[k] = (unsigned)pBl[d][st];
    }
    auto body = [&](int i, int k) {
      const float pOa = __int_as_float(qL[k] << 16);
      const float pObv = __int_as_float(qL[k] & 0xffff0000u);
      const float pB = __int_as_float(qB[k] << 16);
      const float h3 = dpp_wshr1(a3);
      const float n0 = (a0 + h3) * pB;
      const float n1 = fmaf(sk1, h3, a1 + a0) * pOa;
      const float n2 = (a2 + a1) * pB;
      const float n3 = fmaf(sk3, a1, a3 + a2) * pObv;
      const float n4 = (a4 + a3) * pB;
      a0 = n0; a1 = n1; a2 = n2; a3 = n3; a4 = n4;
      const int st2 = stA + i + 4;
      qL[k] = *(const unsigned*)&pO[d][(st2 << 7) + 2 * l];
      qB[k] = (unsigned)pBl[d][st2];
      if (((tbase + i) & 7) == 0) renorm();
    };
    int i = 0;
    for (; i + 4 <= n; i += 4) { body(i, 0); body(i + 1, 1); body(i + 2, 2); body(i + 3, 3); }
    if ((n & 3) > 0) body(i, 0);
    if ((n & 3) > 1) body(i + 1, 1);
    if ((n & 3) > 2) body(i + 2, 2);
  };

  auto run_full = [&](int d) {
    unsigned qL[8], qB[4];
#pragma unroll
    for (int k = 0; k < 8; ++k)
      qL[k] = *(const unsigned*)&pO[d][(k << 7) + 2 * l];
#pragma unroll
    for (int j = 0; j < 4; ++j)
      qB[j] = *(const unsigned*)&pBl[d][2 * j];
    for (int i = 0; i < 64; i += 8) {
#pragma unroll
      for (int k = 0; k < 8; ++k) {
        const float pOa = __int_as_float(qL[k] << 16);
        const float pObv = __int_as_float(qL[k] & 0xffff0000u);
        const unsigned bb = qB[k >> 1];
        const float pB = __int_as_float((k & 1) ? (bb & 0xffff0000u) : (bb << 16));
        const float h3 = dpp_wshr1(a3);
        const float n0 = (a0 + h3) * pB;
        const float n1 = fmaf(sk1, h3, a1 + a0) * pOa;
        const float n2 = (a2 + a1) * pB;
        const float n3 = fmaf(sk3, a1, a3 + a2) * pObv;
        const float n4 = (a4 + a3) * pB;
        a0 = n0; a1 = n1; a2 = n2; a3 = n3; a4 = n4;
        qL[k] = *(const unsigned*)&pO[d][((i + k + 8) << 7) + 2 * l];
        if (k & 1) qB[k >> 1] = *(const unsigned*)&pBl[d][i + k + 7];
        if (k == 0) renorm();
      }
    }
  };

  if (64 < len) stage(1, 1);
  run_dyn(0, 1, (64 < len) ? 64 : len, 1);
  __syncthreads();
  const int Cfull = len >> 6;
  for (int c = 1; c < Cfull; ++c) {
    const int d = c & 1;
    if ((c + 1) * 64 < len) stage(c + 1, d ^ 1);
    run_full(d);
    __syncthreads();
  }
  if (len & 63) run_dyn(Cfull & 1, 0, len & 63, Cfull * 64);

  const int tl = __popcll(__ballot(tg[l] != 0)) + __popcll(__ballot(tg[64 + l] != 0));
  const int s1 = 2 * tl - 1, s2 = 2 * tl;
  float v = 0.f;
  const int sb = 4 * l;
  if (sb == s1 || sb == s2) v += a0;
  if (sb + 1 == s1 || sb + 1 == s2) v += a1;
  if (sb + 2 == s1 || sb + 2 == s2) v += a2;
  if (sb + 3 == s1 || sb + 3 == s2) v += a3;
  if (l == 63 && s2 == 256) v += a4;
#pragma unroll
  for (int off = 1; off < 64; off <<= 1) v += __shfl_xor(v, off);
  if (l == 0)
    out[b] = -((log2f(v) + (float)E - 6.0f * (float)len) * 0.6931471805599453f) / (float)tl;
}

// --------------------------------- launcher ---------------------------------
extern "C" void kernel_launch(void* const* d_in, const int* in_sizes, int n_in,
                              void* d_out, int out_size, void* d_ws, size_t ws_size,
                              hipStream_t stream) {
  const int*   targets = (const int*)d_in[0];
  const float* X       = (const float*)d_in[1];
  const int*   lens    = (const int*)d_in[2];
  const float* W1      = (const float*)d_in[3];
  const float* b1      = (const float*)d_in[4];
  const float* W2      = (const float*)d_in[5];
  const float* b2      = (const float*)d_in[6];
  float* out = (float*)d_out;

  ushort* h       = (ushort*)d_ws;                       // 32768*512 bf16 (33.55 MB)
  ushort* W1T     = h + (size_t)Bq * Tt * Hh;            // 512*512 bf16
  ushort* W2T     = W1T + (size_t)Hh * Hh;               // 1024*512 bf16
  ushort* pOddG   = W2T + (size_t)Vv * Hh;               // 32768*128 bf16 (8.39 MB)
  ushort* pBlankG = pOddG + (size_t)Bq * Tt * Ss;        // 32768 bf16 (+pad tail)

  transpose_cvt2<<<dim3(768), dim3(32, 8), 0, stream>>>(W1, W2, W1T, W2T);
  gemm1_fused<<<dim3((Bq * Tt) / 64), dim3(256), 0, stream>>>(X, W1T, b1, lens, h);
  gemm2sm<<<dim3((Bq * Tt) / 64), dim3(256), 0, stream>>>(h, W2T, b2, targets, lens, pOddG, pBlankG);
  ctc_dp<<<dim3(Bq), dim3(64), 0, stream>>>(pOddG, pBlankG, targets, lens, out);
}

// Round 11
// 229.601 us; speedup vs baseline: 1.5259x; 1.5259x over previous
//
#include <hip/hip_runtime.h>
#include <hip/hip_bf16.h>
#include <math.h>

#define Bq 32
#define Tt 1024
#define Hh 512
#define Vv 1024
#define Ss 128

typedef short bf16x8 __attribute__((ext_vector_type(8)));
typedef float f32x4 __attribute__((ext_vector_type(4)));

#define GLDS(srcp, dstp, sz) \
  __builtin_amdgcn_global_load_lds( \
      (const __attribute__((address_space(1))) void*)(srcp), \
      (__attribute__((address_space(3))) void*)(dstp), sz, 0, 0)

__device__ __forceinline__ ushort f2bf(float v) {
  __hip_bfloat16 hv = __float2bfloat16(v);
  return *(ushort*)&hv;
}

// wait until <=N of this wave's VMEM ops outstanding, then raw workgroup barrier
template <int N>
__device__ __forceinline__ void wb() {
  __asm__ volatile("s_waitcnt vmcnt(%0)" ::"i"(N) : "memory");
  __builtin_amdgcn_s_barrier();
}

// butterfly sum over the 16-lane r16 group
#define BFLY_ADD(v) { \
  v += __int_as_float(__builtin_amdgcn_ds_swizzle(__float_as_int(v), 0x041F)); \
  v += __int_as_float(__builtin_amdgcn_ds_swizzle(__float_as_int(v), 0x081F)); \
  v += __int_as_float(__builtin_amdgcn_ds_swizzle(__float_as_int(v), 0x101F)); \
  v += __int_as_float(__builtin_amdgcn_ds_swizzle(__float_as_int(v), 0x201F)); }

// ---- merged transpose + fp32->bf16 for W1 and W2 in ONE dispatch ----
__global__ void transpose_cvt2(const float* __restrict__ W1, const float* __restrict__ W2,
                               ushort* __restrict__ W1T, ushort* __restrict__ W2T) {
  __shared__ float tile[32][33];
  const int bid = blockIdx.x;
  const float* in; ushort* out; int K, N, bx, by;
  if (bid < 256) { in = W1; out = W1T; K = Hh; N = Hh; bx = bid & 15; by = bid >> 4; }
  else { const int b2 = bid - 256; in = W2; out = W2T; K = Hh; N = Vv; bx = b2 & 31; by = b2 >> 5; }
  const int k0 = by * 32, n0 = bx * 32;
  const int tx = threadIdx.x, ty = threadIdx.y;
  for (int i = ty; i < 32; i += 8)
    tile[i][tx] = in[(size_t)(k0 + i) * N + n0 + tx];
  __syncthreads();
  for (int i = ty; i < 32; i += 8)
    out[(size_t)(n0 + i) * K + k0 + tx] = f2bf(tile[tx][i]);
}

// ---- GEMM1: h = tanh(X @ W1T^T + b1) ----
// 64 rows/block; A-frags once from fp32 X into regs; B 4-buffered (2 pairs)
// via GLDS; 2 k-chunks (32 MFMA) per raw barrier, vmcnt(8) never-drain.
__global__ __launch_bounds__(256, 2)
void gemm1_fused(const float* __restrict__ X, const ushort* __restrict__ Bt,
                 const float* __restrict__ bias, const int* __restrict__ lens,
                 ushort* __restrict__ H) {
  __shared__ ushort Bs[4][128 * 64];          // 64 KB
  const int row0 = blockIdx.x * 64;
  if ((row0 & (Tt - 1)) >= lens[blockIdx.x >> 4]) return;

  const int tid = threadIdx.x;
  const int lane = tid & 63, wave = tid >> 6;
  const int wm = wave >> 1, wn = wave & 1;
  const int q = lane >> 4, r16 = lane & 15;
  const int lrow = lane >> 3;
  const int swz = (lane & 7) ^ lrow;
  const int rx = r16 & 7;
  const int kx0 = (q ^ rx) * 8;
  const int kx1 = ((4 + q) ^ rx) * 8;

  float bcolAll[4][4];
#pragma unroll
  for (int nt = 0; nt < 4; ++nt)
#pragma unroll
    for (int ni = 0; ni < 4; ++ni)
      bcolAll[nt][ni] = bias[nt * 128 + wn * 64 + ni * 16 + r16];

  bf16x8 af[16][2];
#pragma unroll
  for (int ks = 0; ks < 16; ++ks)
#pragma unroll
    for (int mi = 0; mi < 2; ++mi) {
      const float* src = X + (size_t)(row0 + wm * 32 + mi * 16 + r16) * Hh + ks * 32 + q * 8;
      const float4 f0 = *(const float4*)(src);
      const float4 f1 = *(const float4*)(src + 4);
      union { bf16x8 v; ushort u[8]; } pk;
      pk.u[0] = f2bf(f0.x); pk.u[1] = f2bf(f0.y); pk.u[2] = f2bf(f0.z); pk.u[3] = f2bf(f0.w);
      pk.u[4] = f2bf(f1.x); pk.u[5] = f2bf(f1.y); pk.u[6] = f2bf(f1.z); pk.u[7] = f2bf(f1.w);
      af[ks][mi] = pk.v;
    }

  auto stageChunk = [&](int nt2, int kc2, int buf) {
#pragma unroll
    for (int i = 0; i < 4; ++i) {
      const int seg = wave * 4 + i;
      const int rr = seg * 8 + lrow;
      GLDS(Bt + (size_t)(nt2 * 128 + rr) * Hh + kc2 * 64 + swz * 8, &Bs[buf][seg * 512], 16);
    }
  };
  auto readFrags = [&](bf16x8 (&bfr)[2][4], int d) {
#pragma unroll
    for (int ni = 0; ni < 4; ++ni) {
      bfr[0][ni] = *(const bf16x8*)(&Bs[d][((wn * 64 + ni * 16 + r16) << 6) + kx0]);
      bfr[1][ni] = *(const bf16x8*)(&Bs[d][((wn * 64 + ni * 16 + r16) << 6) + kx1]);
    }
  };

  stageChunk(0, 0, 0);     // super-chunk 0 -> pair 0
  stageChunk(0, 1, 1);

  f32x4 acc[2][4];
#pragma unroll
  for (int i = 0; i < 2; ++i)
#pragma unroll
    for (int j = 0; j < 4; ++j) acc[i][j] = (f32x4){0.f, 0.f, 0.f, 0.f};

  for (int nt = 0; nt < 4; ++nt) {
#pragma unroll
    for (int sc = 0; sc < 4; ++sc) {         // super-chunk in tile (2 k-chunks)
      const int p = sc & 1;                  // consume pair (compile-time)
      const int pn = (sc + 1) & 1;           // stage pair
      const bool haveS = !(nt == 3 && sc == 3);
      if (haveS) {
        const int ntn = nt + (sc == 3 ? 1 : 0);
        stageChunk(ntn, (2 * sc + 2) & 7, 2 * pn);
        stageChunk(ntn, (2 * sc + 3) & 7, 2 * pn + 1);
        wb<8>();
      } else {
        wb<0>();
      }
      bf16x8 frA[2][4], frB[2][4];
      readFrags(frA, 2 * p);
      readFrags(frB, 2 * p + 1);
#pragma unroll
      for (int ksl = 0; ksl < 2; ++ksl)
#pragma unroll
        for (int mi = 0; mi < 2; ++mi)
#pragma unroll
          for (int ni = 0; ni < 4; ++ni)
            acc[mi][ni] = __builtin_amdgcn_mfma_f32_16x16x32_bf16(af[4 * sc + ksl][mi], frA[ksl][ni], acc[mi][ni], 0, 0, 0);
#pragma unroll
      for (int ksl = 0; ksl < 2; ++ksl)
#pragma unroll
        for (int mi = 0; mi < 2; ++mi)
#pragma unroll
          for (int ni = 0; ni < 4; ++ni)
            acc[mi][ni] = __builtin_amdgcn_mfma_f32_16x16x32_bf16(af[4 * sc + 2 + ksl][mi], frB[ksl][ni], acc[mi][ni], 0, 0, 0);

      if (sc == 3) {   // tile epilogue
#pragma unroll
        for (int mi = 0; mi < 2; ++mi)
#pragma unroll
          for (int r = 0; r < 4; ++r) {
            const int row = row0 + wm * 32 + mi * 16 + q * 4 + r;
#pragma unroll
            for (int ni = 0; ni < 4; ++ni) {
              const float v = acc[mi][ni][r] + bcolAll[nt][ni];
              const float ex = __expf(2.0f * v);       // tanh=(e^2x-1)/(e^2x+1)
              const float th = (ex - 1.0f) / (ex + 1.0f);
              H[(size_t)row * Hh + nt * 128 + wn * 64 + ni * 16 + r16] = f2bf(th);
            }
            acc[mi][0][r] = 0.f; acc[mi][1][r] = 0.f; acc[mi][2][r] = 0.f; acc[mi][3][r] = 0.f;
          }
      }
    }
  }
}

// ---- GEMM2 + bias + softmax (no-max: |logit|<~2) + label gather, fused ----
// Same 2-chunks-per-barrier pipeline; 8 col-tiles + label tile.
__global__ __launch_bounds__(256, 2)
void gemm2sm(const ushort* __restrict__ Aq, const ushort* __restrict__ Bt,
             const float* __restrict__ bias, const int* __restrict__ tgt,
             const int* __restrict__ lens,
             ushort* __restrict__ pOdd, ushort* __restrict__ pBlank) {
  __shared__ ushort Bs[4][128 * 64];          // 64 KB
  __shared__ float biasLds[Vv];               // 4 KB
  __shared__ int tgLds[128];
  __shared__ float blankL[64];
  __shared__ float rowSum[64];
  __shared__ float tmpP[2][64];

  const int row0 = blockIdx.x * 64;
  const int bEx = blockIdx.x >> 4;
  if ((row0 & (Tt - 1)) >= lens[bEx]) return;

  const int tid = threadIdx.x;
  const int lane = tid & 63, wave = tid >> 6;
  const int wm = wave >> 1, wn = wave & 1;
  const int q = lane >> 4, r16 = lane & 15;
  const int lrow = lane >> 3;
  const int swz = (lane & 7) ^ lrow;
  const int rx = r16 & 7;
  const int kx0 = (q ^ rx) * 8;
  const int kx1 = ((4 + q) ^ rx) * 8;

  bf16x8 af[16][2];
#pragma unroll
  for (int ks = 0; ks < 16; ++ks)
#pragma unroll
    for (int mi = 0; mi < 2; ++mi)
      af[ks][mi] = *(const bf16x8*)(Aq + (size_t)(row0 + wm * 32 + mi * 16 + r16) * Hh + ks * 32 + q * 8);

  GLDS(bias + tid * 4, (char*)biasLds + wave * 1024, 16);
  if (tid < 128) tgLds[tid] = tgt[bEx * Ss + tid];

  auto stageChunk = [&](int nt2, int kc2, int buf) {
#pragma unroll
    for (int i = 0; i < 4; ++i) {
      const int seg = wave * 4 + i;
      const int rr = seg * 8 + lrow;
      const ushort* src = (nt2 < 8)
          ? Bt + (size_t)(nt2 * 128 + rr) * Hh + kc2 * 64 + swz * 8
          : Bt + (size_t)tgLds[rr] * Hh + kc2 * 64 + swz * 8;
      GLDS(src, &Bs[buf][seg * 512], 16);
    }
  };
  auto readFrags = [&](bf16x8 (&bfr)[2][4], int d) {
#pragma unroll
    for (int ni = 0; ni < 4; ++ni) {
      bfr[0][ni] = *(const bf16x8*)(&Bs[d][((wn * 64 + ni * 16 + r16) << 6) + kx0]);
      bfr[1][ni] = *(const bf16x8*)(&Bs[d][((wn * 64 + ni * 16 + r16) << 6) + kx1]);
    }
  };

  __asm__ volatile("s_waitcnt lgkmcnt(0)" ::: "memory");  // tgLds writes done
  stageChunk(0, 0, 0);     // super-chunk 0 -> pair 0
  stageChunk(0, 1, 1);

  f32x4 acc[2][4];
#pragma unroll
  for (int i = 0; i < 2; ++i)
#pragma unroll
    for (int j = 0; j < 4; ++j) acc[i][j] = (f32x4){0.f, 0.f, 0.f, 0.f};
  float rowP[2][4] = {{0.f, 0.f, 0.f, 0.f}, {0.f, 0.f, 0.f, 0.f}};

  for (int nt = 0; nt < 9; ++nt) {
#pragma unroll
    for (int sc = 0; sc < 4; ++sc) {
      const int p = sc & 1;
      const int pn = (sc + 1) & 1;
      const bool haveS = !(nt == 8 && sc == 3);
      if (haveS) {
        const int ntn = nt + (sc == 3 ? 1 : 0);
        stageChunk(ntn, (2 * sc + 2) & 7, 2 * pn);
        stageChunk(ntn, (2 * sc + 3) & 7, 2 * pn + 1);
        wb<8>();
      } else {
        wb<0>();
      }
      bf16x8 frA[2][4], frB[2][4];
      readFrags(frA, 2 * p);
      readFrags(frB, 2 * p + 1);
#pragma unroll
      for (int ksl = 0; ksl < 2; ++ksl)
#pragma unroll
        for (int mi = 0; mi < 2; ++mi)
#pragma unroll
          for (int ni = 0; ni < 4; ++ni)
            acc[mi][ni] = __builtin_amdgcn_mfma_f32_16x16x32_bf16(af[4 * sc + ksl][mi], frA[ksl][ni], acc[mi][ni], 0, 0, 0);
#pragma unroll
      for (int ksl = 0; ksl < 2; ++ksl)
#pragma unroll
        for (int mi = 0; mi < 2; ++mi)
#pragma unroll
          for (int ni = 0; ni < 4; ++ni)
            acc[mi][ni] = __builtin_amdgcn_mfma_f32_16x16x32_bf16(af[4 * sc + 2 + ksl][mi], frB[ksl][ni], acc[mi][ni], 0, 0, 0);

      if (sc == 3) {
        if (nt < 8) {
          float bcol[4];
#pragma unroll
          for (int ni = 0; ni < 4; ++ni) bcol[ni] = biasLds[nt * 128 + wn * 64 + ni * 16 + r16];
          if (nt == 0 && wn == 0 && r16 == 0) {
#pragma unroll
            for (int mi = 0; mi < 2; ++mi)
#pragma unroll
              for (int r = 0; r < 4; ++r)
                blankL[wm * 32 + mi * 16 + q * 4 + r] = acc[mi][0][r] + bcol[0];
          }
#pragma unroll
          for (int mi = 0; mi < 2; ++mi)
#pragma unroll
            for (int r = 0; r < 4; ++r) {
              float s = __expf(acc[mi][0][r] + bcol[0]);
              s += __expf(acc[mi][1][r] + bcol[1]);
              s += __expf(acc[mi][2][r] + bcol[2]);
              s += __expf(acc[mi][3][r] + bcol[3]);
              rowP[mi][r] += s;
              acc[mi][0][r] = 0.f; acc[mi][1][r] = 0.f; acc[mi][2][r] = 0.f; acc[mi][3][r] = 0.f;
            }
          if (nt == 7) {
            float sred[2][4];
#pragma unroll
            for (int mi = 0; mi < 2; ++mi)
#pragma unroll
              for (int r = 0; r < 4; ++r) {
                float s = rowP[mi][r];
                BFLY_ADD(s);
                sred[mi][r] = s;
              }
            if (r16 == 0) {
#pragma unroll
              for (int mi = 0; mi < 2; ++mi) {
                float4 w = {sred[mi][0], sred[mi][1], sred[mi][2], sred[mi][3]};
                *(float4*)&tmpP[wn][wm * 32 + mi * 16 + q * 4] = w;
              }
            }
            __syncthreads();
            if (tid < 64) {
              const float tot = tmpP[0][tid] + tmpP[1][tid];
              rowSum[tid] = tot;
              pBlank[row0 + tid] = f2bf(__expf(blankL[tid]) * 64.0f / tot);
            }
            __syncthreads();
          }
        } else {
          // label tile: p = exp(logit)/rowSum, prescaled by 2^6
          float bcl[4];
#pragma unroll
          for (int ni = 0; ni < 4; ++ni) bcl[ni] = biasLds[tgLds[wn * 64 + ni * 16 + r16]];
#pragma unroll
          for (int mi = 0; mi < 2; ++mi) {
            const float4 rs4 = *(const float4*)&rowSum[wm * 32 + mi * 16 + q * 4];
#pragma unroll
            for (int r = 0; r < 4; ++r) {
              const float sc2 = 64.0f / ((const float*)&rs4)[r];
              const int row = row0 + wm * 32 + mi * 16 + q * 4 + r;
#pragma unroll
              for (int ni = 0; ni < 4; ++ni) {
                const float pv = __expf(acc[mi][ni][r] + bcl[ni]) * sc2;
                pOdd[(size_t)row * Ss + wn * 64 + ni * 16 + r16] = f2bf(pv);
              }
            }
          }
        }
      }
    }
  }
}

// ---- DPP helpers ----
__device__ __forceinline__ float dpp_wshr1(float x) {
  return __int_as_float(__builtin_amdgcn_update_dpp(
      0, __float_as_int(x), 0x138, 0xf, 0xf, true));
}
__device__ __forceinline__ float dpp_wave_max(float m) {
  m = fmaxf(m, __int_as_float(__builtin_amdgcn_update_dpp(0, __float_as_int(m), 0x111, 0xf, 0xf, true)));
  m = fmaxf(m, __int_as_float(__builtin_amdgcn_update_dpp(0, __float_as_int(m), 0x112, 0xf, 0xf, true)));
  m = fmaxf(m, __int_as_float(__builtin_amdgcn_update_dpp(0, __float_as_int(m), 0x114, 0xf, 0xf, true)));
  m = fmaxf(m, __int_as_float(__builtin_amdgcn_update_dpp(0, __float_as_int(m), 0x118, 0xf, 0xf, true)));
  m = fmaxf(m, __int_as_float(__builtin_amdgcn_update_dpp(__float_as_int(m), __float_as_int(m), 0x142, 0xf, 0xf, false)));
  m = fmaxf(m, __int_as_float(__builtin_amdgcn_update_dpp(__float_as_int(m), __float_as_int(m), 0x143, 0xf, 0xf, false)));
  return __int_as_float(__builtin_amdgcn_readlane(__float_as_int(m), 63));
}

// ---- CTC forward DP: 4 states/lane (+256 on lane63), DPP halo,
// padded double-buffered LDS staging, 8-deep pipeline, unrolled 64-step chunks.
__global__ __launch_bounds__(64)
void ctc_dp(const ushort* __restrict__ pOddG, const ushort* __restrict__ pBlankG,
            const int* __restrict__ tgt, const int* __restrict__ lens,
            float* __restrict__ out) {
  __shared__ ushort pO[2][72 * 128];
  __shared__ ushort pBl[2][128];
  const int b = blockIdx.x, l = threadIdx.x;
  const ushort* pObase = pOddG + (size_t)b * Tt * Ss;
  const ushort* pBbase = pBlankG + (size_t)b * Tt;
  const int* tg = tgt + b * Ss;
  const int len = lens[b];

  float sk1 = 0.f, sk3;
  if (l >= 1) sk1 = (tg[2 * l] != tg[2 * l - 1]) ? 1.f : 0.f;
  sk3 = (tg[2 * l + 1] != tg[2 * l]) ? 1.f : 0.f;

  auto stage = [&](int c, int d) {
    const ushort* src = pObase + (size_t)c * 64 * 128;
#pragma unroll
    for (int i = 0; i < 16; ++i)
      GLDS(src + (i * 64 + l) * 8, &pO[d][i * 512], 16);
    GLDS(pBbase + c * 64 + l * 2, &pBl[d][0], 4);
  };

  stage(0, 0);
  __syncthreads();

  float a0 = 0.f, a1 = 0.f, a2 = 0.f, a3 = 0.f, a4 = 0.f;
  if (l == 0) {
    a0 = __int_as_float(((unsigned)pBl[0][0]) << 16);
    a1 = __int_as_float(((unsigned)pO[0][0]) << 16);
  }
  int E = 0;

  auto renorm = [&]() {
    float m = fmaxf(fmaxf(fmaxf(a0, a1), fmaxf(a2, a3)), a4);
    const float gm = dpp_wave_max(m);
    const int e = (int)((__float_as_uint(gm) >> 23) & 255) - 127;
    int sh = 30 - e; if (sh > 120) sh = 120;
    const float scale = __uint_as_float((unsigned)(127 + sh) << 23);
    E -= sh;
    a0 *= scale; a1 *= scale; a2 *= scale; a3 *= scale; a4 *= scale;
  };

  auto run_dyn = [&](int d, int stA, int stB, int tbase) {
    const int n = stB - stA;
    if (n <= 0) return;
    unsigned qL[4], qB[4];
#pragma unroll
    for (int k = 0; k < 4; ++k) {
      const int st = stA + k;
      qL[k] = *(const unsigned*)&pO[d][(st << 7) + 2 * l];
      qB[k] = (unsigned)pBl[d][st];
    }
    auto body = [&](int i, int k) {
      const float pOa = __int_as_float(qL[k] << 16);
      const float pObv = __int_as_float(qL[k] & 0xffff0000u);
      const float pB = __int_as_float(qB[k] << 16);
      const float h3 = dpp_wshr1(a3);
      const float n0 = (a0 + h3) * pB;
      const float n1 = fmaf(sk1, h3, a1 + a0) * pOa;
      const float n2 = (a2 + a1) * pB;
      const float n3 = fmaf(sk3, a1, a3 + a2) * pObv;
      const float n4 = (a4 + a3) * pB;
      a0 = n0; a1 = n1; a2 = n2; a3 = n3; a4 = n4;
      const int st2 = stA + i + 4;
      qL[k] = *(const unsigned*)&pO[d][(st2 << 7) + 2 * l];
      qB[k] = (unsigned)pBl[d][st2];
      if (((tbase + i) & 7) == 0) renorm();
    };
    int i = 0;
    for (; i + 4 <= n; i += 4) { body(i, 0); body(i + 1, 1); body(i + 2, 2); body(i + 3, 3); }
    if ((n & 3) > 0) body(i, 0);
    if ((n & 3) > 1) body(i + 1, 1);
    if ((n & 3) > 2) body(i + 2, 2);
  };

  auto run_full = [&](int d) {
    unsigned qL[8], qB[4];
#pragma unroll
    for (int k = 0; k < 8; ++k)
      qL[k] = *(const unsigned*)&pO[d][(k << 7) + 2 * l];
#pragma unroll
    for (int j = 0; j < 4; ++j)
      qB[j] = *(const unsigned*)&pBl[d][2 * j];
    for (int i = 0; i < 64; i += 8) {
#pragma unroll
      for (int k = 0; k < 8; ++k) {
        const float pOa = __int_as_float(qL[k] << 16);
        const float pObv = __int_as_float(qL[k] & 0xffff0000u);
        const unsigned bb = qB[k >> 1];
        const float pB = __int_as_float((k & 1) ? (bb & 0xffff0000u) : (bb << 16));
        const float h3 = dpp_wshr1(a3);
        const float n0 = (a0 + h3) * pB;
        const float n1 = fmaf(sk1, h3, a1 + a0) * pOa;
        const float n2 = (a2 + a1) * pB;
        const float n3 = fmaf(sk3, a1, a3 + a2) * pObv;
        const float n4 = (a4 + a3) * pB;
        a0 = n0; a1 = n1; a2 = n2; a3 = n3; a4 = n4;
        qL[k] = *(const unsigned*)&pO[d][((i + k + 8) << 7) + 2 * l];
        if (k & 1) qB[k >> 1] = *(const unsigned*)&pBl[d][i + k + 7];
        if (k == 0) renorm();
      }
    }
  };

  if (64 < len) stage(1, 1);
  run_dyn(0, 1, (64 < len) ? 64 : len, 1);
  __syncthreads();
  const int Cfull = len >> 6;
  for (int c = 1; c < Cfull; ++c) {
    const int d = c & 1;
    if ((c + 1) * 64 < len) stage(c + 1, d ^ 1);
    run_full(d);
    __syncthreads();
  }
  if (len & 63) run_dyn(Cfull & 1, 0, len & 63, Cfull * 64);

  const int tl = __popcll(__ballot(tg[l] != 0)) + __popcll(__ballot(tg[64 + l] != 0));
  const int s1 = 2 * tl - 1, s2 = 2 * tl;
  float v = 0.f;
  const int sb = 4 * l;
  if (sb == s1 || sb == s2) v += a0;
  if (sb + 1 == s1 || sb + 1 == s2) v += a1;
  if (sb + 2 == s1 || sb + 2 == s2) v += a2;
  if (sb + 3 == s1 || sb + 3 == s2) v += a3;
  if (l == 63 && s2 == 256) v += a4;
#pragma unroll
  for (int off = 1; off < 64; off <<= 1) v += __shfl_xor(v, off);
  if (l == 0)
    out[b] = -((log2f(v) + (float)E - 6.0f * (float)len) * 0.6931471805599453f) / (float)tl;
}

// --------------------------------- launcher ---------------------------------
extern "C" void kernel_launch(void* const* d_in, const int* in_sizes, int n_in,
                              void* d_out, int out_size, void* d_ws, size_t ws_size,
                              hipStream_t stream) {
  const int*   targets = (const int*)d_in[0];
  const float* X       = (const float*)d_in[1];
  const int*   lens    = (const int*)d_in[2];
  const float* W1      = (const float*)d_in[3];
  const float* b1      = (const float*)d_in[4];
  const float* W2      = (const float*)d_in[5];
  const float* b2      = (const float*)d_in[6];
  float* out = (float*)d_out;

  ushort* h       = (ushort*)d_ws;                       // 32768*512 bf16 (33.55 MB)
  ushort* W1T     = h + (size_t)Bq * Tt * Hh;            // 512*512 bf16
  ushort* W2T     = W1T + (size_t)Hh * Hh;               // 1024*512 bf16
  ushort* pOddG   = W2T + (size_t)Vv * Hh;               // 32768*128 bf16 (8.39 MB)
  ushort* pBlankG = pOddG + (size_t)Bq * Tt * Ss;        // 32768 bf16 (+pad tail)

  transpose_cvt2<<<dim3(768), dim3(32, 8), 0, stream>>>(W1, W2, W1T, W2T);
  gemm1_fused<<<dim3((Bq * Tt) / 64), dim3(256), 0, stream>>>(X, W1T, b1, lens, h);
  gemm2sm<<<dim3((Bq * Tt) / 64), dim3(256), 0, stream>>>(h, W2T, b2, targets, lens, pOddG, pBlankG);
  ctc_dp<<<dim3(Bq), dim3(64), 0, stream>>>(pOddG, pBlankG, targets, lens, out);
}